// Round 2
// baseline (1185.752 us; speedup 1.0000x reference)
//
#include <hip/hip_runtime.h>
#include <hip/hip_bf16.h>
#include <stdint.h>

#define NNODES 100000
#define NEDGES 1600000

// ---------------- histogram of in-degree (excl. self-loop) ----------------

__global__ __launch_bounds__(256) void k_zero(int* __restrict__ p, int n) {
    int i = blockIdx.x * 256 + threadIdx.x;
    if (i < n) p[i] = 0;
}

__global__ __launch_bounds__(256) void k_hist(const int* __restrict__ dst,
                                              int* __restrict__ hist, int e) {
    int i = blockIdx.x * 256 + threadIdx.x;
    if (i < e) atomicAdd(&hist[dst[i]], 1);
}

__global__ __launch_bounds__(256) void k_dis(const int* __restrict__ hist,
                                             float* __restrict__ dis, int n) {
    int i = blockIdx.x * 256 + threadIdx.x;
    if (i < n) dis[i] = rsqrtf((float)hist[i] + 1.0f);   // +1 self loop
}

// ---------------- two-level exclusive scan over hist (N bins) ----------------

__global__ __launch_bounds__(256) void k_scan1(const int* __restrict__ hist,
                                               int* __restrict__ excl,
                                               int* __restrict__ partials, int n) {
    __shared__ int s[256];
    int t = threadIdx.x;
    int i = blockIdx.x * 256 + t;
    int v = (i < n) ? hist[i] : 0;
    s[t] = v; __syncthreads();
    for (int off = 1; off < 256; off <<= 1) {
        int u = (t >= off) ? s[t - off] : 0;
        __syncthreads();
        s[t] += u;
        __syncthreads();
    }
    if (i < n) excl[i] = s[t] - v;
    if (t == 255) partials[blockIdx.x] = s[255];
}

__global__ __launch_bounds__(512) void k_scan2(int* __restrict__ partials, int nb) {
    __shared__ int s[512];
    int t = threadIdx.x;
    int v = (t < nb) ? partials[t] : 0;
    s[t] = v; __syncthreads();
    for (int off = 1; off < 512; off <<= 1) {
        int u = (t >= off) ? s[t - off] : 0;
        __syncthreads();
        s[t] += u;
        __syncthreads();
    }
    if (t < nb) partials[t] = s[t] - v;   // exclusive
}

__global__ __launch_bounds__(256) void k_scan3(const int* __restrict__ excl,
                                               const int* __restrict__ partials,
                                               int* __restrict__ row_start,
                                               int* __restrict__ cursor, int n, int e) {
    int i = blockIdx.x * 256 + threadIdx.x;
    if (i < n) {
        int v = excl[i] + partials[blockIdx.x];
        row_start[i] = v;
        cursor[i] = v;
    }
    if (i == 0) row_start[n] = e;
}

// ---------------- placement: perm[pos within dst-row] = src ----------------

__global__ __launch_bounds__(256) void k_place(const int* __restrict__ src,
                                               const int* __restrict__ dst,
                                               int* __restrict__ cursor,
                                               int* __restrict__ perm, int e) {
    int i = blockIdx.x * 256 + threadIdx.x;
    if (i < e) {
        int p = atomicAdd(&cursor[dst[i]], 1);
        perm[p] = src[i];
    }
}

// ---------------- copy x into h-region (cols 0..127, row stride 512) ----------------

__global__ __launch_bounds__(256) void k_copy_x(const float* __restrict__ x,
                                                float* __restrict__ hreg, int n) {
    int i = blockIdx.x * 256 + threadIdx.x;
    if (i >= n * 32) return;
    int v = i >> 5, c4 = i & 31;
    float4 val = ((const float4*)(x + (size_t)v * 128))[c4];
    *(float4*)(hreg + (size_t)v * 512 + c4 * 4) = val;
}

// ---------------- f32 GEMM: g[r] = (X[r] @ W) * dis[r] ----------------
// tile: 64 rows x 128 cols per block of 256 threads; thread: 4 rows x 8 cols

__global__ __launch_bounds__(256) void k_gemm(const float* __restrict__ X, int ldx,
                                              const float* __restrict__ W,
                                              const float* __restrict__ dis,
                                              float* __restrict__ g, int n) {
    __shared__ float Ws[128 * 128];      // [k][c] row-major, 64 KB
    __shared__ float xs[64][129];        // padded, 33 KB
    int t = threadIdx.x;
    int base = blockIdx.x * 64;

    for (int i = t; i < 4096; i += 256)
        ((float4*)Ws)[i] = ((const float4*)W)[i];

    for (int i = t; i < 64 * 32; i += 256) {
        int r = i >> 5, c4 = i & 31;
        int row = base + r;
        float4 v = make_float4(0.f, 0.f, 0.f, 0.f);
        if (row < n) v = ((const float4*)(X + (size_t)row * ldx))[c4];
        *(float4*)&xs[r][c4 * 4] = v;
    }
    __syncthreads();

    int cg = t & 15;       // 16 col groups
    int rg = t >> 4;       // 16 row groups of 4 rows
    int c0 = cg * 4, c1 = 64 + cg * 4;
    float a[4][8] = {};

    for (int k = 0; k < 128; k += 4) {
        float4 xv[4];
        #pragma unroll
        for (int i = 0; i < 4; ++i) xv[i] = *(const float4*)&xs[rg * 4 + i][k];
        #pragma unroll
        for (int kk = 0; kk < 4; ++kk) {
            float4 w0 = *(const float4*)&Ws[(k + kk) * 128 + c0];
            float4 w1 = *(const float4*)&Ws[(k + kk) * 128 + c1];
            #pragma unroll
            for (int i = 0; i < 4; ++i) {
                float xk = ((const float*)&xv[i])[kk];
                a[i][0] += xk * w0.x; a[i][1] += xk * w0.y;
                a[i][2] += xk * w0.z; a[i][3] += xk * w0.w;
                a[i][4] += xk * w1.x; a[i][5] += xk * w1.y;
                a[i][6] += xk * w1.z; a[i][7] += xk * w1.w;
            }
        }
    }

    #pragma unroll
    for (int i = 0; i < 4; ++i) {
        int row = base + rg * 4 + i;
        if (row >= n) continue;
        float dv = dis[row];
        float4 v0 = make_float4(a[i][0] * dv, a[i][1] * dv, a[i][2] * dv, a[i][3] * dv);
        float4 v1 = make_float4(a[i][4] * dv, a[i][5] * dv, a[i][6] * dv, a[i][7] * dv);
        *(float4*)(g + (size_t)row * 128 + c0) = v0;
        *(float4*)(g + (size_t)row * 128 + c1) = v1;
    }
}

// ---------------- gather: out[v] = (g[v] + sum_{u->v} g[u]) * dis[v] + b ----------------
// one wave per node; float2 per lane (128 cols / 64 lanes)

__global__ __launch_bounds__(256) void k_gather(const float* __restrict__ g,
                                                const int* __restrict__ row_start,
                                                const int* __restrict__ perm,
                                                const float* __restrict__ dis,
                                                const float* __restrict__ b,
                                                float* __restrict__ hcol,   // pre-offset, stride 512
                                                int n) {
    int w = (int)((blockIdx.x * 256u + threadIdx.x) >> 6);
    if (w >= n) return;
    int lane = threadIdx.x & 63;
    int beg = row_start[w], end = row_start[w + 1];

    float2 a = ((const float2*)(g + (size_t)w * 128))[lane];   // self loop

    int ei = beg;
    for (; ei + 3 < end; ei += 4) {
        int s0 = perm[ei], s1 = perm[ei + 1], s2 = perm[ei + 2], s3 = perm[ei + 3];
        float2 v0 = ((const float2*)(g + (size_t)s0 * 128))[lane];
        float2 v1 = ((const float2*)(g + (size_t)s1 * 128))[lane];
        float2 v2 = ((const float2*)(g + (size_t)s2 * 128))[lane];
        float2 v3 = ((const float2*)(g + (size_t)s3 * 128))[lane];
        a.x += v0.x + v1.x + v2.x + v3.x;
        a.y += v0.y + v1.y + v2.y + v3.y;
    }
    for (; ei < end; ++ei) {
        int s = perm[ei];
        float2 v = ((const float2*)(g + (size_t)s * 128))[lane];
        a.x += v.x; a.y += v.y;
    }

    float dv = dis[w];
    float2 bb = ((const float2*)b)[lane];
    float2 o = make_float2(a.x * dv + bb.x, a.y * dv + bb.y);
    ((float2*)(hcol + (size_t)w * 512))[lane] = o;
}

// ---------------- final linear: pred = h @ W_lin + b_lin  ([N,512]@[512,16]) ----------------

__global__ __launch_bounds__(256) void k_final(const float* __restrict__ h,   // stride 512
                                               const float* __restrict__ Wl,  // [512][16]
                                               const float* __restrict__ bl,
                                               float* __restrict__ out, int n) {
    __shared__ float sWt[16][516];  // transposed W_lin, padded
    __shared__ float sh[16][516];
    int t = threadIdx.x;
    for (int i = t; i < 8192; i += 256) {
        int k = i >> 4, j = i & 15;
        sWt[j][k] = Wl[i];
    }
    int base = blockIdx.x * 16;
    for (int i = t; i < 16 * 128; i += 256) {
        int r = i >> 7, c4 = i & 127;
        float4 v = ((const float4*)(h + (size_t)(base + r) * 512))[c4];
        *(float4*)&sh[r][c4 * 4] = v;
    }
    __syncthreads();
    int node = t >> 4, j = t & 15;
    float acc = bl[j];
    const float4* shp = (const float4*)&sh[node][0];
    const float4* swp = (const float4*)&sWt[j][0];
    #pragma unroll 4
    for (int k4 = 0; k4 < 128; ++k4) {
        float4 a = shp[k4], b = swp[k4];
        acc += a.x * b.x + a.y * b.y + a.z * b.z + a.w * b.w;
    }
    out[(size_t)(base + node) * 16 + j] = acc;
}

// ---------------- launcher ----------------

extern "C" void kernel_launch(void* const* d_in, const int* in_sizes, int n_in,
                              void* d_out, int out_size, void* d_ws, size_t ws_size,
                              hipStream_t stream) {
    const float* x  = (const float*)d_in[0];
    const int* edges = (const int*)d_in[1];
    const int* src = edges;            // edge_index[0]
    const int* dst = edges + NEDGES;   // edge_index[1]
    const float* W1 = (const float*)d_in[2];
    const float* b1 = (const float*)d_in[3];
    const float* W2 = (const float*)d_in[4];
    const float* b2 = (const float*)d_in[5];
    const float* W3 = (const float*)d_in[6];
    const float* b3 = (const float*)d_in[7];
    const float* Wl = (const float*)d_in[8];
    const float* bl = (const float*)d_in[9];

    float* outp = (float*)d_out;
    float* pred = outp;                        // [N,16]
    float* hreg = outp + (size_t)NNODES * 16;  // [N,512] h_unmasked

    // workspace layout (g first: keeps 16B alignment for float4 access)
    float* g   = (float*)d_ws;                       // N*128
    float* dis = g + (size_t)NNODES * 128;           // N
    int* hist      = (int*)(dis + NNODES);           // N
    int* excl      = hist + NNODES;                  // N
    int* partials  = excl + NNODES;                  // 512
    int* row_start = partials + 512;                 // N+1
    int* cursor    = row_start + NNODES + 1;         // N
    int* perm      = cursor + NNODES;                // E

    int n = NNODES, e = NEDGES;
    int nb = (n + 255) / 256;   // 391 scan blocks (<= 512)

    // ---- degree + CSR build (once) ----
    k_zero<<<nb, 256, 0, stream>>>(hist, n);
    k_hist<<<(e + 255) / 256, 256, 0, stream>>>(dst, hist, e);
    k_dis<<<nb, 256, 0, stream>>>(hist, dis, n);
    k_scan1<<<nb, 256, 0, stream>>>(hist, excl, partials, n);
    k_scan2<<<1, 512, 0, stream>>>(partials, nb);
    k_scan3<<<nb, 256, 0, stream>>>(excl, partials, row_start, cursor, n, e);
    k_place<<<(e + 255) / 256, 256, 0, stream>>>(src, dst, cursor, perm, e);

    k_copy_x<<<(n * 32 + 255) / 256, 256, 0, stream>>>(x, hreg, n);

    const float* Wmats[3] = {W1, W2, W3};
    const float* bvecs[3] = {b1, b2, b3};
    for (int L = 0; L < 3; ++L) {
        const float* Xin = (L == 0) ? x : (hreg + 128 * L);
        int ldx = (L == 0) ? 128 : 512;
        float* hcol = hreg + 128 * (L + 1);
        k_gemm<<<(n + 63) / 64, 256, 0, stream>>>(Xin, ldx, Wmats[L], dis, g, n);
        k_gather<<<(n * 64 + 255) / 256, 256, 0, stream>>>(g, row_start, perm, dis,
                                                           bvecs[L], hcol, n);
    }
    k_final<<<n / 16, 256, 0, stream>>>(hreg, Wl, bl, pred, n);
}

// Round 3
// 715.419 us; speedup vs baseline: 1.6574x; 1.6574x over previous
//
#include <hip/hip_runtime.h>
#include <hip/hip_bf16.h>
#include <stdint.h>

#define NNODES 100000
#define NEDGES 1600000
#define NB 196   // dst buckets of 512 nodes: 196*512 = 100352 >= 100000

typedef __attribute__((ext_vector_type(8))) short bf16x8;
typedef __attribute__((ext_vector_type(4))) float f32x4;
typedef __attribute__((ext_vector_type(4))) unsigned short us4;

__device__ __forceinline__ unsigned short f2bf(float f) {
    unsigned int u = __float_as_uint(f);
    unsigned int r = (u + 0x7fffu + ((u >> 16) & 1u)) >> 16;   // RNE
    return (unsigned short)r;
}
__device__ __forceinline__ float bfhi(unsigned int v) { return __uint_as_float(v & 0xffff0000u); }
__device__ __forceinline__ float bflo(unsigned int v) { return __uint_as_float(v << 16); }

// ---------------- CSR build: bucket histogram ----------------

__global__ __launch_bounds__(256) void k_zero_i(int* __restrict__ p, int n) {
    int i = blockIdx.x * 256 + threadIdx.x;
    if (i < n) p[i] = 0;
}

__global__ __launch_bounds__(256) void k_bkt_hist(const int* __restrict__ dst,
                                                  int* __restrict__ bkt_cnt, int e) {
    __shared__ int cnt[NB];
    int t = threadIdx.x;
    if (t < NB) cnt[t] = 0;
    __syncthreads();
    int base = blockIdx.x * 4096;
    #pragma unroll
    for (int k = 0; k < 16; ++k) {
        int i = base + k * 256 + t;
        if (i < e) atomicAdd(&cnt[dst[i] >> 9], 1);
    }
    __syncthreads();
    if (t < NB && cnt[t]) atomicAdd(&bkt_cnt[t], cnt[t]);
}

__global__ __launch_bounds__(256) void k_bkt_scan(const int* __restrict__ bkt_cnt,
                                                  int* __restrict__ bkt_base,
                                                  int* __restrict__ bcursor,
                                                  int* __restrict__ row_start, int e, int n) {
    __shared__ int s[256];
    int t = threadIdx.x;
    int v = (t < NB) ? bkt_cnt[t] : 0;
    s[t] = v; __syncthreads();
    for (int off = 1; off < 256; off <<= 1) {
        int u = (t >= off) ? s[t - off] : 0;
        __syncthreads();
        s[t] += u;
        __syncthreads();
    }
    if (t < NB) { int ex = s[t] - v; bkt_base[t] = ex; bcursor[t] = ex; }
    if (t == 0) { bkt_base[NB] = e; row_start[n] = e; }
}

// bucketize edges into tmp: grouped by dst>>9, payload (src<<9)|(dst&511)

__global__ __launch_bounds__(256) void k_bucketize(const int* __restrict__ src,
                                                   const int* __restrict__ dst,
                                                   int* __restrict__ bcursor,
                                                   int* __restrict__ tmp, int e) {
    __shared__ int cnt[NB];
    __shared__ int gbase[NB];
    int t = threadIdx.x;
    if (t < NB) cnt[t] = 0;
    __syncthreads();
    int base = blockIdx.x * 4096;
    int off[16], pk[16];
    #pragma unroll
    for (int k = 0; k < 16; ++k) {
        int i = base + k * 256 + t;
        off[k] = -1;
        if (i < e) {
            int s = src[i], d = dst[i];
            int b = d >> 9;
            off[k] = atomicAdd(&cnt[b], 1) | (b << 16);   // off<4096, b<196
            pk[k] = (s << 9) | (d & 511);
        }
    }
    __syncthreads();
    if (t < NB && cnt[t]) gbase[t] = atomicAdd(&bcursor[t], cnt[t]);
    __syncthreads();
    #pragma unroll
    for (int k = 0; k < 16; ++k) {
        if (off[k] >= 0) {
            int b = off[k] >> 16, o = off[k] & 0xffff;
            tmp[gbase[b] + o] = pk[k];
        }
    }
}

// per-bucket: LDS hist(512) + scan -> row_start, dis, perm (no global atomics)

__global__ __launch_bounds__(256) void k_csr(const int* __restrict__ bkt_base,
                                             const int* __restrict__ tmp,
                                             int* __restrict__ perm,
                                             int* __restrict__ row_start,
                                             float* __restrict__ dis, int n) {
    __shared__ int cnt[512], sA[512], sB[512];
    int b = blockIdx.x, t = threadIdx.x;
    int beg = bkt_base[b], end = bkt_base[b + 1];
    int node0 = b << 9;
    int nnode = n - node0; if (nnode > 512) nnode = 512;
    cnt[t] = 0; cnt[t + 256] = 0;
    __syncthreads();
    for (int i = beg + t; i < end; i += 256)
        atomicAdd(&cnt[tmp[i] & 511], 1);
    __syncthreads();
    int* cur = sA; int* nxt = sB;
    cur[t] = cnt[t]; cur[t + 256] = cnt[t + 256];
    __syncthreads();
    for (int off = 1; off < 512; off <<= 1) {
        for (int j = t; j < 512; j += 256)
            nxt[j] = cur[j] + ((j >= off) ? cur[j - off] : 0);
        __syncthreads();
        int* tp = cur; cur = nxt; nxt = tp;
    }
    // cur = inclusive scan
    for (int j = t; j < 512; j += 256) {
        int rs = beg + cur[j] - cnt[j];
        if (j < nnode) {
            row_start[node0 + j] = rs;
            dis[node0 + j] = rsqrtf((float)cnt[j] + 1.0f);
        }
        nxt[j] = rs;   // becomes the placement cursor
    }
    __syncthreads();
    for (int i = beg + t; i < end; i += 256) {
        int v = tmp[i];
        int p = atomicAdd(&nxt[v & 511], 1);
        perm[p] = v >> 9;
    }
}

// ---------------- copy x into h-region (cols 0..127, row stride 512) ----------------

__global__ __launch_bounds__(256) void k_copy_x(const float* __restrict__ x,
                                                float* __restrict__ hreg, int n) {
    int i = blockIdx.x * 256 + threadIdx.x;
    if (i >= n * 32) return;
    int v = i >> 5, c4 = i & 31;
    float4 val = ((const float4*)(x + (size_t)v * 128))[c4];
    *(float4*)(hreg + (size_t)v * 512 + c4 * 4) = val;
}

// ---------------- MFMA bf16 GEMM: g[r] = bf16( (X[r] @ W) * dis[r] ) ----------------
// block 256 = 4 waves, tile 128x128, wave tile 64x64, 16x16x32 mfma

__global__ __launch_bounds__(256) void k_gemm_mfma(const float* __restrict__ X, int ldx,
                                                   const float* __restrict__ W,
                                                   const float* __restrict__ dis,
                                                   unsigned short* __restrict__ g, int n) {
    __shared__ unsigned short As[128 * 128];   // [row][k] bf16, XOR-swizzled
    __shared__ unsigned short Bs[128 * 128];   // Wt[n][k] bf16, XOR-swizzled
    __shared__ float sdis[128];
    int t = threadIdx.x;
    int base = blockIdx.x * 128;

    // W [k][n] f32 -> Bs transposed bf16
    #pragma unroll
    for (int j = 0; j < 16; ++j) {
        int i4 = t + j * 256;
        int k = i4 >> 5, n4 = (i4 & 31) * 4;
        float4 w = ((const float4*)W)[i4];
        Bs[((n4 + 0) * 128 + k) ^ (((n4 + 0) & 7) << 3)] = f2bf(w.x);
        Bs[((n4 + 1) * 128 + k) ^ (((n4 + 1) & 7) << 3)] = f2bf(w.y);
        Bs[((n4 + 2) * 128 + k) ^ (((n4 + 2) & 7) << 3)] = f2bf(w.z);
        Bs[((n4 + 3) * 128 + k) ^ (((n4 + 3) & 7) << 3)] = f2bf(w.w);
    }
    // X tile -> As bf16
    #pragma unroll
    for (int j = 0; j < 16; ++j) {
        int i4 = t + j * 256;
        int row = i4 >> 5, c4 = i4 & 31;
        int rg = base + row; if (rg >= n) rg = n - 1;   // clamp; garbage rows unused
        float4 xv = *(const float4*)(X + (size_t)rg * ldx + c4 * 4);
        us4 u; u.x = f2bf(xv.x); u.y = f2bf(xv.y); u.z = f2bf(xv.z); u.w = f2bf(xv.w);
        int idx = (row * 128 + c4 * 4) ^ ((row & 7) << 3);
        *(us4*)&As[idx] = u;
    }
    if (t < 128) { int rg = base + t; sdis[t] = (rg < n) ? dis[rg] : 0.f; }
    __syncthreads();

    int w = t >> 6, l = t & 63;
    int wm = (w >> 1) * 64, wn = (w & 1) * 64;
    int lr = l & 15, lq = l >> 4;
    f32x4 acc[4][4] = {};
    #pragma unroll
    for (int ks = 0; ks < 4; ++ks) {
        bf16x8 a[4], bb[4];
        #pragma unroll
        for (int mi = 0; mi < 4; ++mi) {
            int row = wm + mi * 16 + lr;
            a[mi] = *(const bf16x8*)&As[(row * 128 + ks * 32 + lq * 8) ^ ((row & 7) << 3)];
        }
        #pragma unroll
        for (int ni = 0; ni < 4; ++ni) {
            int col = wn + ni * 16 + lr;
            bb[ni] = *(const bf16x8*)&Bs[(col * 128 + ks * 32 + lq * 8) ^ ((col & 7) << 3)];
        }
        #pragma unroll
        for (int mi = 0; mi < 4; ++mi)
            #pragma unroll
            for (int ni = 0; ni < 4; ++ni)
                acc[mi][ni] = __builtin_amdgcn_mfma_f32_16x16x32_bf16(a[mi], bb[ni], acc[mi][ni], 0, 0, 0);
    }

    #pragma unroll
    for (int mi = 0; mi < 4; ++mi) {
        #pragma unroll
        for (int r = 0; r < 4; ++r) {
            int rl = wm + mi * 16 + lq * 4 + r;
            int grow = base + rl;
            if (grow < n) {
                float dv = sdis[rl];
                #pragma unroll
                for (int ni = 0; ni < 4; ++ni) {
                    int col = wn + ni * 16 + lr;
                    g[(size_t)grow * 128 + col] = f2bf(acc[mi][ni][r] * dv);
                }
            }
        }
    }
}

// ---------------- gather: hcol[v] = (g[v] + sum g[u]) * dis[v] + bias ----------------
// one wave per node; ushort2 (4B) per lane = full 256B row per iteration

__global__ __launch_bounds__(256) void k_gather(const unsigned short* __restrict__ g,
                                                const int* __restrict__ row_start,
                                                const int* __restrict__ perm,
                                                const float* __restrict__ dis,
                                                const float* __restrict__ bias,
                                                float* __restrict__ hcol,   // pre-offset, stride 512
                                                int n) {
    int w = (int)((blockIdx.x * 256u + threadIdx.x) >> 6);
    if (w >= n) return;
    int lane = threadIdx.x & 63;
    int beg = row_start[w], end = row_start[w + 1];

    unsigned int v = *(const unsigned int*)(g + (size_t)w * 128 + lane * 2);
    float ax = bflo(v), ay = bfhi(v);

    int ei = beg;
    for (; ei + 7 < end; ei += 8) {
        unsigned int u0 = *(const unsigned int*)(g + (size_t)perm[ei + 0] * 128 + lane * 2);
        unsigned int u1 = *(const unsigned int*)(g + (size_t)perm[ei + 1] * 128 + lane * 2);
        unsigned int u2 = *(const unsigned int*)(g + (size_t)perm[ei + 2] * 128 + lane * 2);
        unsigned int u3 = *(const unsigned int*)(g + (size_t)perm[ei + 3] * 128 + lane * 2);
        unsigned int u4 = *(const unsigned int*)(g + (size_t)perm[ei + 4] * 128 + lane * 2);
        unsigned int u5 = *(const unsigned int*)(g + (size_t)perm[ei + 5] * 128 + lane * 2);
        unsigned int u6 = *(const unsigned int*)(g + (size_t)perm[ei + 6] * 128 + lane * 2);
        unsigned int u7 = *(const unsigned int*)(g + (size_t)perm[ei + 7] * 128 + lane * 2);
        ax += (bflo(u0) + bflo(u1)) + (bflo(u2) + bflo(u3)) + (bflo(u4) + bflo(u5)) + (bflo(u6) + bflo(u7));
        ay += (bfhi(u0) + bfhi(u1)) + (bfhi(u2) + bfhi(u3)) + (bfhi(u4) + bfhi(u5)) + (bfhi(u6) + bfhi(u7));
    }
    for (; ei < end; ++ei) {
        unsigned int u = *(const unsigned int*)(g + (size_t)perm[ei] * 128 + lane * 2);
        ax += bflo(u); ay += bfhi(u);
    }

    float dv = dis[w];
    float2 bb = ((const float2*)bias)[lane];
    float2 o = make_float2(ax * dv + bb.x, ay * dv + bb.y);
    ((float2*)(hcol + (size_t)w * 512))[lane] = o;
}

// ---------------- final linear: pred = h @ W_lin + b_lin ----------------

__global__ __launch_bounds__(256) void k_final(const float* __restrict__ h,   // stride 512
                                               const float* __restrict__ Wl,  // [512][16]
                                               const float* __restrict__ bl,
                                               float* __restrict__ out, int n) {
    __shared__ float sWt[16][516];
    __shared__ float sh[16][516];
    int t = threadIdx.x;
    for (int i = t; i < 8192; i += 256) {
        int k = i >> 4, j = i & 15;
        sWt[j][k] = Wl[i];
    }
    int base = blockIdx.x * 16;
    for (int i = t; i < 16 * 128; i += 256) {
        int r = i >> 7, c4 = i & 127;
        float4 v = ((const float4*)(h + (size_t)(base + r) * 512))[c4];
        *(float4*)&sh[r][c4 * 4] = v;
    }
    __syncthreads();
    int node = t >> 4, j = t & 15;
    float acc = bl[j];
    const float4* shp = (const float4*)&sh[node][0];
    const float4* swp = (const float4*)&sWt[j][0];
    #pragma unroll 4
    for (int k4 = 0; k4 < 128; ++k4) {
        float4 a = shp[k4], b = swp[k4];
        acc += a.x * b.x + a.y * b.y + a.z * b.z + a.w * b.w;
    }
    out[(size_t)(base + node) * 16 + j] = acc;
}

// ---------------- launcher ----------------

extern "C" void kernel_launch(void* const* d_in, const int* in_sizes, int n_in,
                              void* d_out, int out_size, void* d_ws, size_t ws_size,
                              hipStream_t stream) {
    const float* x  = (const float*)d_in[0];
    const int* edges = (const int*)d_in[1];
    const int* src = edges;            // edge_index[0]
    const int* dst = edges + NEDGES;   // edge_index[1]
    const float* W1 = (const float*)d_in[2];
    const float* b1 = (const float*)d_in[3];
    const float* W2 = (const float*)d_in[4];
    const float* b2 = (const float*)d_in[5];
    const float* W3 = (const float*)d_in[6];
    const float* b3 = (const float*)d_in[7];
    const float* Wl = (const float*)d_in[8];
    const float* bl = (const float*)d_in[9];

    float* outp = (float*)d_out;
    float* pred = outp;                        // [N,16]
    float* hreg = outp + (size_t)NNODES * 16;  // [N,512] h_unmasked

    unsigned short* g = (unsigned short*)d_ws;             // N*128 bf16
    float* dis   = (float*)(g + (size_t)NNODES * 128);     // N
    int* tmp     = (int*)(dis + NNODES);                   // E
    int* perm    = tmp + NEDGES;                           // E
    int* row_start = perm + NEDGES;                        // N+1
    int* bkt_cnt  = row_start + NNODES + 1;                // NB
    int* bkt_base = bkt_cnt + NB;                          // NB+1
    int* bcursor  = bkt_base + NB + 1;                     // NB

    int n = NNODES, e = NEDGES;
    int eb = (e + 4095) / 4096;   // 391

    k_zero_i<<<1, 256, 0, stream>>>(bkt_cnt, NB);
    k_bkt_hist<<<eb, 256, 0, stream>>>(dst, bkt_cnt, e);
    k_bkt_scan<<<1, 256, 0, stream>>>(bkt_cnt, bkt_base, bcursor, row_start, e, n);
    k_bucketize<<<eb, 256, 0, stream>>>(src, dst, bcursor, tmp, e);
    k_csr<<<NB, 256, 0, stream>>>(bkt_base, tmp, perm, row_start, dis, n);

    k_copy_x<<<(n * 32 + 255) / 256, 256, 0, stream>>>(x, hreg, n);

    const float* Wmats[3] = {W1, W2, W3};
    const float* bvecs[3] = {b1, b2, b3};
    for (int L = 0; L < 3; ++L) {
        const float* Xin = (L == 0) ? x : (hreg + 128 * L);
        int ldx = (L == 0) ? 128 : 512;
        float* hcol = hreg + 128 * (L + 1);
        k_gemm_mfma<<<(n + 127) / 128, 256, 0, stream>>>(Xin, ldx, Wmats[L], dis, g, n);
        k_gather<<<(n * 64 + 255) / 256, 256, 0, stream>>>(g, row_start, perm, dis,
                                                           bvecs[L], hcol, n);
    }
    k_final<<<n / 16, 256, 0, stream>>>(hreg, Wl, bl, pred, n);
}